// Round 6
// baseline (976.521 us; speedup 1.0000x reference)
//
#include <hip/hip_runtime.h>

#define N_NODES 30000
#define N_EDGES 150000
#define N_REL 10
#define DIM 256

#define N_TILES ((N_NODES + 63) / 64)   // 469
#define NBINS (N_TILES * N_REL)         // 4690 per direction
#define NBINS2 (2 * NBINS)              // 9380

#define ACC_S 260                       // accf row stride (floats), breaks pow2 banks

typedef __attribute__((ext_vector_type(8))) short bf16x8;
typedef __attribute__((ext_vector_type(4))) float f32x4;

__device__ __forceinline__ unsigned short f2bf(float f) {
  union { float f; unsigned int u; } v; v.f = f;
  unsigned int u = v.u;
  unsigned int r = u + 0x7fffu + ((u >> 16) & 1u);  // RNE
  return (unsigned short)(r >> 16);
}

// ---- preprocessing -------------------------------------------------------

__global__ void conv_x_kernel(const float* __restrict__ x,
                              unsigned short* __restrict__ xbf) {
  int idx = blockIdx.x * blockDim.x + threadIdx.x;  // one float4 each, exact grid
  float4 v = reinterpret_cast<const float4*>(x)[idx];
  ushort4 o;
  o.x = f2bf(v.x); o.y = f2bf(v.y); o.z = f2bf(v.z); o.w = f2bf(v.w);
  reinterpret_cast<ushort4*>(xbf)[idx] = o;
}

// wt[b][o][i] = W_b[i][o] (bf16), buckets: 0..9 fwd, 10..19 rev, 20 self
__global__ void conv_w_kernel(const float* __restrict__ Wf,
                              const float* __restrict__ Wr,
                              const float* __restrict__ Ws,
                              unsigned short* __restrict__ wt) {
  int idx = blockIdx.x * blockDim.x + threadIdx.x;  // exact grid 21*65536
  int b = idx >> 16;
  int t = idx & 65535;
  int o = t >> 8, i = t & 255;
  const float* src = (b < N_REL) ? (Wf + (size_t)b * 65536)
                   : (b < 2 * N_REL) ? (Wr + (size_t)(b - N_REL) * 65536)
                   : Ws;
  wt[idx] = f2bf(src[i * 256 + o]);
}

// ---- counting sort by (dst_tile, rel) per direction ----------------------

__global__ void zero_bins_kernel(int* __restrict__ bins) {
  int i = blockIdx.x * blockDim.x + threadIdx.x;
  if (i < NBINS2) bins[i] = 0;
}

__global__ void hist2_kernel(const int* __restrict__ dep,
                             const int* __restrict__ rel,
                             const int* __restrict__ gov,
                             int* __restrict__ bins) {
  int e = blockIdx.x * blockDim.x + threadIdx.x;
  if (e < N_EDGES) {
    int r = rel[e];
    atomicAdd(&bins[(dep[e] >> 6) * N_REL + r], 1);            // fwd keyed by dep
    atomicAdd(&bins[NBINS + (gov[e] >> 6) * N_REL + r], 1);    // rev keyed by gov
  }
}

// single-block scan over all 9380 bins -> rp2 (exclusive) + cursor copy
__global__ void scan_bins_kernel(const int* __restrict__ bins,
                                 int* __restrict__ rp2,
                                 int* __restrict__ cursor) {
  __shared__ int part[256];
  const int CH = (NBINS2 + 255) / 256;  // 37
  int t = threadIdx.x;
  int b0 = t * CH;
  int s = 0;
  for (int i = 0; i < CH; ++i) {
    int j = b0 + i;
    if (j < NBINS2) s += bins[j];
  }
  part[t] = s;
  __syncthreads();
  for (int off = 1; off < 256; off <<= 1) {
    int add = (t >= off) ? part[t - off] : 0;
    __syncthreads();
    part[t] += add;
    __syncthreads();
  }
  int run = (t == 0) ? 0 : part[t - 1];
  for (int i = 0; i < CH; ++i) {
    int j = b0 + i;
    if (j < NBINS2) {
      rp2[j] = run;
      cursor[j] = run;
      run += bins[j];
    }
  }
  if (t == 255) rp2[NBINS2] = run;
}

// ev[pos] = (src<<6) | local_dst  (src fits 15 bits)
__global__ void scatter_edges_kernel(const int* __restrict__ dep,
                                     const int* __restrict__ rel,
                                     const int* __restrict__ gov,
                                     int* __restrict__ cursor,
                                     int* __restrict__ ev) {
  int e = blockIdx.x * blockDim.x + threadIdx.x;
  if (e < N_EDGES) {
    int d = dep[e], g = gov[e], r = rel[e];
    int pf = atomicAdd(&cursor[(d >> 6) * N_REL + r], 1);
    ev[pf] = (g << 6) | (d & 63);                          // fwd: src=gov -> dep
    int pr = atomicAdd(&cursor[NBINS + (g >> 6) * N_REL + r], 1);
    ev[pr] = (d << 6) | (g & 63);                          // rev: src=dep -> gov
  }
}

// ---- fused per-tile kernel: self GEMM + all edge GEMMs + single out write

__global__ void fused_tile_kernel(const unsigned short* __restrict__ xbf,
                                  const unsigned short* __restrict__ wt,
                                  const float* __restrict__ b_self,
                                  const float* __restrict__ b_fwd,
                                  const float* __restrict__ b_rev,
                                  const int* __restrict__ rp2,
                                  const int* __restrict__ ev,
                                  float* __restrict__ out) {
  const int tile = blockIdx.x;
  const int n0 = tile * 64;
  const int nrows = min(64, N_NODES - n0);
  const int tid = threadIdx.x;
  const int wave = tid >> 6, lane = tid & 63;
  const int lm = lane & 15, q = lane >> 4;
  const int nb = wave * 64;

  __shared__ float accf[64 * ACC_S];  // 66560 B; column stripes wave-private
  __shared__ int s_sd[64];

  // ---- self pass: accf[row][col] = (x[n0+row] @ W_self)[col] + b_self[col]
  {
    const unsigned short* wr[4];
    #pragma unroll
    for (int ni = 0; ni < 4; ++ni)
      wr[ni] = wt + (size_t)20 * DIM * DIM + (size_t)(nb + ni * 16 + lm) * DIM + q * 8;
    const unsigned short* xr[4];
    #pragma unroll
    for (int mi = 0; mi < 4; ++mi) {
      int r = n0 + mi * 16 + lm;
      int rc = r < N_NODES ? r : N_NODES - 1;
      xr[mi] = xbf + (size_t)rc * DIM + q * 8;
    }
    f32x4 acc[4][4];
    #pragma unroll
    for (int mi = 0; mi < 4; ++mi)
      #pragma unroll
      for (int ni = 0; ni < 4; ++ni)
        acc[mi][ni] = (f32x4){0.f, 0.f, 0.f, 0.f};
    #pragma unroll
    for (int k0 = 0; k0 < DIM; k0 += 32) {
      bf16x8 a[4], b[4];
      #pragma unroll
      for (int mi = 0; mi < 4; ++mi) a[mi] = *reinterpret_cast<const bf16x8*>(xr[mi] + k0);
      #pragma unroll
      for (int ni = 0; ni < 4; ++ni) b[ni] = *reinterpret_cast<const bf16x8*>(wr[ni] + k0);
      #pragma unroll
      for (int mi = 0; mi < 4; ++mi)
        #pragma unroll
        for (int ni = 0; ni < 4; ++ni)
          acc[mi][ni] = __builtin_amdgcn_mfma_f32_16x16x32_bf16(a[mi], b[ni], acc[mi][ni], 0, 0, 0);
    }
    float bias[4];
    #pragma unroll
    for (int ni = 0; ni < 4; ++ni) bias[ni] = b_self[nb + ni * 16 + lm];
    #pragma unroll
    for (int mi = 0; mi < 4; ++mi)
      #pragma unroll
      for (int reg = 0; reg < 4; ++reg) {
        int row = mi * 16 + q * 4 + reg;
        #pragma unroll
        for (int ni = 0; ni < 4; ++ni)
          accf[row * ACC_S + nb + ni * 16 + lm] = acc[mi][ni][reg] + bias[ni];
      }
  }

  // ---- edge passes: accumulate messages into accf via LDS atomics
  for (int dir = 0; dir < 2; ++dir) {
    const float* bias_base = (dir == 0) ? b_fwd : b_rev;
    for (int r = 0; r < N_REL; ++r) {
      int key = dir * NBINS + tile * N_REL + r;
      int beg = rp2[key], end = rp2[key + 1];
      int cnt = end - beg;
      if (cnt == 0) continue;
      const unsigned short* wb =
          wt + (size_t)(dir * N_REL + r) * DIM * DIM;
      float bias[4];
      #pragma unroll
      for (int ni = 0; ni < 4; ++ni)
        bias[ni] = bias_base[r * DIM + nb + ni * 16 + lm];

      for (int sub = 0; sub < cnt; sub += 64) {
        int rows_valid = min(64, cnt - sub);
        __syncthreads();  // protect s_sd reuse
        if (tid < 64)
          s_sd[tid] = (tid < rows_valid) ? ev[beg + sub + tid] : 0;
        __syncthreads();
        int mmax = (rows_valid + 15) >> 4;

        f32x4 acc[4][4];
        #pragma unroll
        for (int mi = 0; mi < 4; ++mi)
          #pragma unroll
          for (int ni = 0; ni < 4; ++ni)
            acc[mi][ni] = (f32x4){0.f, 0.f, 0.f, 0.f};

        #pragma unroll
        for (int k0 = 0; k0 < DIM; k0 += 32) {
          bf16x8 b[4];
          #pragma unroll
          for (int ni = 0; ni < 4; ++ni)
            b[ni] = *reinterpret_cast<const bf16x8*>(
                wb + (size_t)(nb + ni * 16 + lm) * DIM + k0 + q * 8);
          #pragma unroll
          for (int mi = 0; mi < 4; ++mi) {
            if (mi < mmax) {
              int src = s_sd[mi * 16 + lm] >> 6;
              bf16x8 a = *reinterpret_cast<const bf16x8*>(
                  xbf + (size_t)src * DIM + k0 + q * 8);
              #pragma unroll
              for (int ni = 0; ni < 4; ++ni)
                acc[mi][ni] = __builtin_amdgcn_mfma_f32_16x16x32_bf16(
                    a, b[ni], acc[mi][ni], 0, 0, 0);
            }
          }
        }

        #pragma unroll
        for (int mi = 0; mi < 4; ++mi) {
          if (mi < mmax) {
            #pragma unroll
            for (int reg = 0; reg < 4; ++reg) {
              int row = mi * 16 + q * 4 + reg;
              if (row < rows_valid) {
                int ld = s_sd[row] & 63;
                #pragma unroll
                for (int ni = 0; ni < 4; ++ni)
                  atomicAdd(&accf[ld * ACC_S + nb + ni * 16 + lm],
                            acc[mi][ni][reg] + bias[ni]);
              }
            }
          }
        }
      }
    }
  }

  __syncthreads();

  // ---- single coalesced fp32 write of the tile
  #pragma unroll
  for (int it = 0; it < 16; ++it) {
    int idx = it * 1024 + tid * 4;  // 64*256 floats total
    int row = idx >> 8, col = idx & 255;
    if (row < nrows) {
      float4 v;
      v.x = accf[row * ACC_S + col];
      v.y = accf[row * ACC_S + col + 1];
      v.z = accf[row * ACC_S + col + 2];
      v.w = accf[row * ACC_S + col + 3];
      *reinterpret_cast<float4*>(out + (size_t)(n0 + row) * DIM + col) = v;
    }
  }
}

// ---- launch --------------------------------------------------------------

extern "C" void kernel_launch(void* const* d_in, const int* in_sizes, int n_in,
                              void* d_out, int out_size, void* d_ws, size_t ws_size,
                              hipStream_t stream) {
  const float* x      = (const float*)d_in[0];
  const float* W_self = (const float*)d_in[1];
  const float* b_self = (const float*)d_in[2];
  const float* W_fwd  = (const float*)d_in[3];
  const float* b_fwd  = (const float*)d_in[4];
  const float* W_rev  = (const float*)d_in[5];
  const float* b_rev  = (const float*)d_in[6];
  const int* dep = (const int*)d_in[7];
  const int* rel = (const int*)d_in[8];
  const int* gov = (const int*)d_in[9];
  float* out = (float*)d_out;

  char* base = (char*)d_ws;
  size_t off = 0;
  auto alloc = [&](size_t bytes) -> char* {
    char* p = base + off;
    off = (off + bytes + 15) & ~(size_t)15;
    return p;
  };

  unsigned short* xbf = (unsigned short*)alloc((size_t)N_NODES * DIM * 2);   // 15.36 MB
  unsigned short* wt  = (unsigned short*)alloc((size_t)21 * DIM * DIM * 2);  // 2.75 MB
  int* bins   = (int*)alloc((size_t)NBINS2 * 4);
  int* rp2    = (int*)alloc((size_t)(NBINS2 + 1) * 4);
  int* cursor = (int*)alloc((size_t)NBINS2 * 4);
  int* ev     = (int*)alloc((size_t)2 * N_EDGES * 4);                        // 1.2 MB
  (void)ws_size;

  conv_x_kernel<<<N_NODES * DIM / 4 / 256, 256, 0, stream>>>(x, xbf);
  conv_w_kernel<<<21 * DIM * DIM / 256, 256, 0, stream>>>(W_fwd, W_rev, W_self, wt);
  zero_bins_kernel<<<(NBINS2 + 255) / 256, 256, 0, stream>>>(bins);
  hist2_kernel<<<(N_EDGES + 255) / 256, 256, 0, stream>>>(dep, rel, gov, bins);
  scan_bins_kernel<<<1, 256, 0, stream>>>(bins, rp2, cursor);
  scatter_edges_kernel<<<(N_EDGES + 255) / 256, 256, 0, stream>>>(dep, rel, gov, cursor, ev);
  fused_tile_kernel<<<N_TILES, 256, 0, stream>>>(
      xbf, wt, b_self, b_fwd, b_rev, rp2, ev, out);
}

// Round 7
// 329.069 us; speedup vs baseline: 2.9675x; 2.9675x over previous
//
#include <hip/hip_runtime.h>

#define N_NODES 30000
#define N_EDGES 150000
#define N_REL 10
#define DIM 256

#define SORT_BLOCKS 120
#define SORT_CHUNK ((N_EDGES + SORT_BLOCKS - 1) / SORT_BLOCKS)  // 1250

#define SCAN_CHUNK 256
#define SCAN_BLOCKS ((N_NODES + SCAN_CHUNK - 1) / SCAN_CHUNK)   // 118

// LDS A-tile row stride: 280 shorts = 560 B (16B-aligned, breaks pow2 banks)
#define A_STRIDE 280

typedef __attribute__((ext_vector_type(8))) short bf16x8;
typedef __attribute__((ext_vector_type(4))) float f32x4;

__device__ __forceinline__ unsigned short f2bf(float f) {
  union { float f; unsigned int u; } v; v.f = f;
  unsigned int u = v.u;
  unsigned int r = u + 0x7fffu + ((u >> 16) & 1u);  // RNE
  return (unsigned short)(r >> 16);
}

// ---- preprocessing -------------------------------------------------------

__global__ void conv_x_kernel(const float* __restrict__ x,
                              unsigned short* __restrict__ xbf) {
  int idx = blockIdx.x * blockDim.x + threadIdx.x;  // one float4 each, exact grid
  float4 v = reinterpret_cast<const float4*>(x)[idx];
  ushort4 o;
  o.x = f2bf(v.x); o.y = f2bf(v.y); o.z = f2bf(v.z); o.w = f2bf(v.w);
  reinterpret_cast<ushort4*>(xbf)[idx] = o;
}

// wt[b][o][i] = W_b[i][o] (bf16), buckets: 0..9 fwd, 10..19 rev, 20 self
__global__ void conv_w_kernel(const float* __restrict__ Wf,
                              const float* __restrict__ Wr,
                              const float* __restrict__ Ws,
                              unsigned short* __restrict__ wt) {
  int idx = blockIdx.x * blockDim.x + threadIdx.x;  // exact grid 21*65536
  int b = idx >> 16;
  int t = idx & 65535;
  int o = t >> 8, i = t & 255;
  const float* src = (b < N_REL) ? (Wf + (size_t)b * 65536)
                   : (b < 2 * N_REL) ? (Wr + (size_t)(b - N_REL) * 65536)
                   : Ws;
  wt[idx] = f2bf(src[i * 256 + o]);
}

// ---- counting sort by relation (block-local hist, no global atomics) -----

__global__ void blockhist_kernel(const int* __restrict__ rel,
                                 int* __restrict__ block_counts) {
  __shared__ int h[N_REL];
  if (threadIdx.x < N_REL) h[threadIdx.x] = 0;
  __syncthreads();
  int beg = blockIdx.x * SORT_CHUNK;
  int end = min(beg + SORT_CHUNK, N_EDGES);
  for (int e = beg + threadIdx.x; e < end; e += blockDim.x)
    atomicAdd(&h[rel[e]], 1);
  __syncthreads();
  if (threadIdx.x < N_REL)
    block_counts[blockIdx.x * N_REL + threadIdx.x] = h[threadIdx.x];
}

__global__ void scan_rel_kernel(const int* __restrict__ block_counts,
                                int* __restrict__ rel_start,
                                int* __restrict__ block_offset) {
  __shared__ int tot[N_REL];
  int r = threadIdx.x;
  if (r < N_REL) {
    int s = 0;
    for (int b = 0; b < SORT_BLOCKS; ++b) s += block_counts[b * N_REL + r];
    tot[r] = s;
  }
  __syncthreads();
  if (threadIdx.x == 0) {
    int s = 0;
    for (int i = 0; i < N_REL; ++i) { rel_start[i] = s; s += tot[i]; }
    rel_start[N_REL] = s;
  }
  __syncthreads();
  if (r < N_REL) {
    int run = rel_start[r];
    for (int b = 0; b < SORT_BLOCKS; ++b) {
      block_offset[b * N_REL + r] = run;
      run += block_counts[b * N_REL + r];
    }
  }
}

__global__ void scatter2_kernel(const int* __restrict__ rel,
                                const int* __restrict__ block_offset,
                                int* __restrict__ perm) {
  __shared__ int cur[N_REL];
  if (threadIdx.x < N_REL)
    cur[threadIdx.x] = block_offset[blockIdx.x * N_REL + threadIdx.x];
  __syncthreads();
  int beg = blockIdx.x * SORT_CHUNK;
  int end = min(beg + SORT_CHUNK, N_EDGES);
  for (int e = beg + threadIdx.x; e < end; e += blockDim.x) {
    int pos = atomicAdd(&cur[rel[e]], 1);  // LDS atomic, cheap
    perm[pos] = e;
  }
}

// ---- destination CSR (rp by dst; col = perm-position of each msg) --------

__global__ void zero_cnt_kernel(int* __restrict__ cnt, int n) {
  int i = blockIdx.x * blockDim.x + threadIdx.x;
  if (i < n) cnt[i] = 0;
}

__global__ void hist_dst_kernel(const int* __restrict__ dep,
                                const int* __restrict__ gov,
                                int* __restrict__ cnt) {
  int e = blockIdx.x * blockDim.x + threadIdx.x;
  if (e < N_EDGES) {
    atomicAdd(&cnt[dep[e]], 1);
    atomicAdd(&cnt[N_NODES + gov[e]], 1);
  }
}

__global__ void scanA_kernel(const int* __restrict__ cnt,
                             int* __restrict__ tmp, int* __restrict__ sums) {
  __shared__ int s[SCAN_CHUNK];
  int d = blockIdx.y, b = blockIdx.x, t = threadIdx.x;
  int i = b * SCAN_CHUNK + t;
  int v = (i < N_NODES) ? cnt[d * N_NODES + i] : 0;
  s[t] = v;
  __syncthreads();
  for (int off = 1; off < SCAN_CHUNK; off <<= 1) {
    int add = (t >= off) ? s[t - off] : 0;
    __syncthreads();
    s[t] += add;
    __syncthreads();
  }
  if (i < N_NODES) tmp[d * N_NODES + i] = s[t] - v;  // exclusive
  if (t == SCAN_CHUNK - 1) sums[d * SCAN_BLOCKS + b] = s[t];
}

__global__ void scanB_kernel(const int* __restrict__ sums,
                             int* __restrict__ chunk_off, int* __restrict__ rp) {
  __shared__ int s[128];
  int d = blockIdx.x, t = threadIdx.x;
  int v = (t < SCAN_BLOCKS) ? sums[d * SCAN_BLOCKS + t] : 0;
  s[t] = v;
  __syncthreads();
  for (int off = 1; off < 128; off <<= 1) {
    int add = (t >= off) ? s[t - off] : 0;
    __syncthreads();
    s[t] += add;
    __syncthreads();
  }
  if (t < SCAN_BLOCKS) chunk_off[d * SCAN_BLOCKS + t] = s[t] - v;
  if (t == 127) rp[d * (N_NODES + 1) + N_NODES] = s[127];
}

__global__ void scanC_kernel(const int* __restrict__ tmp,
                             const int* __restrict__ chunk_off,
                             int* __restrict__ rp, int* __restrict__ cursor) {
  int d = blockIdx.y;
  int i = blockIdx.x * SCAN_CHUNK + threadIdx.x;
  if (i < N_NODES) {
    int v = tmp[d * N_NODES + i] + chunk_off[d * SCAN_BLOCKS + blockIdx.x];
    rp[d * (N_NODES + 1) + i] = v;
    cursor[d * N_NODES + i] = v;
  }
}

// col lists hold msg ROW indices (= perm positions p), keyed by destination
__global__ void colidx_kernel(const int* __restrict__ perm,
                              const int* __restrict__ dep,
                              const int* __restrict__ gov,
                              int* __restrict__ cursor,
                              int* __restrict__ colf,
                              int* __restrict__ colr) {
  int p = blockIdx.x * blockDim.x + threadIdx.x;
  if (p < N_EDGES) {
    int e = perm[p];
    colf[atomicAdd(&cursor[dep[e]], 1)] = p;             // fwd msg p -> dep
    colr[atomicAdd(&cursor[N_NODES + gov[e]], 1)] = p;   // rev msg p -> gov
  }
}

// ---- self GEMM: out = x @ W_self + b_self (plain stores, runs first) -----

__global__ __launch_bounds__(256, 2)
void self_gemm_kernel(const unsigned short* __restrict__ xbf,
                      const unsigned short* __restrict__ wt_self,
                      const float* __restrict__ b_self,
                      float* __restrict__ out) {
  const int tid = threadIdx.x;
  const int wave = tid >> 6, lane = tid & 63;
  const int lm = lane & 15, q = lane >> 4;
  const int nb = wave * 64;

  // hoisted, loop-invariant W fragments: 8 k-steps x 4 ni = 128 VGPRs
  bf16x8 wf[8][4];
  #pragma unroll
  for (int kk = 0; kk < 8; ++kk)
    #pragma unroll
    for (int ni = 0; ni < 4; ++ni)
      wf[kk][ni] = *reinterpret_cast<const bf16x8*>(
          wt_self + (size_t)(nb + ni * 16 + lm) * DIM + kk * 32 + q * 8);

  float bias[4];
  #pragma unroll
  for (int ni = 0; ni < 4; ++ni) bias[ni] = b_self[nb + ni * 16 + lm];

  const int ntiles = (N_NODES + 63) / 64;
  for (int t = blockIdx.x; t < ntiles; t += gridDim.x) {
    const int row0 = t * 64;
    const unsigned short* xr[4];
    #pragma unroll
    for (int mi = 0; mi < 4; ++mi) {
      int r = row0 + mi * 16 + lm;
      int rc = r < N_NODES ? r : N_NODES - 1;
      xr[mi] = xbf + (size_t)rc * DIM + q * 8;
    }

    f32x4 acc[4][4];
    #pragma unroll
    for (int mi = 0; mi < 4; ++mi)
      #pragma unroll
      for (int ni = 0; ni < 4; ++ni)
        acc[mi][ni] = (f32x4){0.f, 0.f, 0.f, 0.f};

    #pragma unroll
    for (int kk = 0; kk < 8; ++kk) {
      bf16x8 a[4];
      #pragma unroll
      for (int mi = 0; mi < 4; ++mi)
        a[mi] = *reinterpret_cast<const bf16x8*>(xr[mi] + kk * 32);
      #pragma unroll
      for (int mi = 0; mi < 4; ++mi)
        #pragma unroll
        for (int ni = 0; ni < 4; ++ni)
          acc[mi][ni] = __builtin_amdgcn_mfma_f32_16x16x32_bf16(a[mi], wf[kk][ni], acc[mi][ni], 0, 0, 0);
    }

    #pragma unroll
    for (int mi = 0; mi < 4; ++mi) {
      #pragma unroll
      for (int reg = 0; reg < 4; ++reg) {
        int row = row0 + mi * 16 + q * 4 + reg;  // C/D: row = quad*4 + reg
        if (row < N_NODES) {
          #pragma unroll
          for (int ni = 0; ni < 4; ++ni)
            out[(size_t)row * DIM + nb + ni * 16 + lm] = acc[mi][ni][reg] + bias[ni];
        }
      }
    }
  }
}

// ---- phase 1: both directions, rel-bucketed GEMM, hoisted W --------------
// bucket 0..9 = fwd (src=gov), 10..19 = rev (src=dep). msg row for rev is
// offset by N_EDGES. msg row layout = natural columns (bf16).

__global__ __launch_bounds__(256, 2)
void edge_gemm_p1_kernel(const unsigned short* __restrict__ xbf,
                         const unsigned short* __restrict__ wt,
                         const float* __restrict__ b_fwd,
                         const float* __restrict__ b_rev,
                         const int* __restrict__ perm,
                         const int* __restrict__ rel_start,
                         const int* __restrict__ dep,
                         const int* __restrict__ gov,
                         unsigned short* __restrict__ msg) {
  const int bkt = blockIdx.y;
  const int r = bkt % N_REL;
  const bool fwd = bkt < N_REL;
  const int* src_idx = fwd ? gov : dep;
  unsigned short* mdir = msg + (fwd ? 0 : (size_t)N_EDGES * DIM);
  const int beg = rel_start[r];
  const int cnt = rel_start[r + 1] - beg;
  const int ntiles = (cnt + 63) >> 6;

  const int tid = threadIdx.x;
  const int wave = tid >> 6, lane = tid & 63;
  const int lm = lane & 15, q = lane >> 4;
  const int nb = wave * 64;

  __shared__ int s_src[64];
  __shared__ unsigned short sA[64 * A_STRIDE];  // 35840 B; reused by epilogue

  // hoisted, tile-invariant W fragments (128 VGPRs, amortized over ~5 tiles)
  bf16x8 wf[8][4];
  const unsigned short* wbase = wt + (size_t)bkt * DIM * DIM;
  #pragma unroll
  for (int kk = 0; kk < 8; ++kk)
    #pragma unroll
    for (int ni = 0; ni < 4; ++ni)
      wf[kk][ni] = *reinterpret_cast<const bf16x8*>(
          wbase + (size_t)(nb + ni * 16 + lm) * DIM + kk * 32 + q * 8);

  const float* bptr = (fwd ? b_fwd : b_rev) + r * DIM;
  float bias[4];
  #pragma unroll
  for (int ni = 0; ni < 4; ++ni) bias[ni] = bptr[nb + ni * 16 + lm];

  for (int t = blockIdx.x; t < ntiles; t += gridDim.x) {
    const int tile0 = t << 6;
    const int rows_valid = min(64, cnt - tile0);

    if (tid < 64) {
      int s = 0;
      if (tid < rows_valid) s = src_idx[perm[beg + tile0 + tid]];
      s_src[tid] = s;
    }
    __syncthreads();

    // stage 64 gathered x rows into LDS (each row fetched exactly once)
    {
      int half = lane >> 5;        // 0 or 1
      int lcol = lane & 31;        // 16B chunk index within row
      #pragma unroll
      for (int i = 0; i < 8; ++i) {
        int row = wave * 16 + i * 2 + half;
        uint4 v = *reinterpret_cast<const uint4*>(
            xbf + (size_t)s_src[row] * DIM + lcol * 8);
        *reinterpret_cast<uint4*>(sA + row * A_STRIDE + lcol * 8) = v;
      }
    }
    __syncthreads();

    f32x4 acc[4][4];
    #pragma unroll
    for (int mi = 0; mi < 4; ++mi)
      #pragma unroll
      for (int ni = 0; ni < 4; ++ni)
        acc[mi][ni] = (f32x4){0.f, 0.f, 0.f, 0.f};

    // pure LDS-read + MFMA k-loop (W is in registers)
    #pragma unroll
    for (int kk = 0; kk < 8; ++kk) {
      bf16x8 a[4];
      #pragma unroll
      for (int mi = 0; mi < 4; ++mi)
        a[mi] = *reinterpret_cast<const bf16x8*>(
            sA + (mi * 16 + lm) * A_STRIDE + kk * 32 + q * 8);
      #pragma unroll
      for (int mi = 0; mi < 4; ++mi)
        #pragma unroll
        for (int ni = 0; ni < 4; ++ni)
          acc[mi][ni] = __builtin_amdgcn_mfma_f32_16x16x32_bf16(a[mi], wf[kk][ni], acc[mi][ni], 0, 0, 0);
    }
    __syncthreads();  // k-loop done; sA free for epilogue transpose

    // transpose acc to natural [row][col] bf16 layout in LDS
    #pragma unroll
    for (int mi = 0; mi < 4; ++mi)
      #pragma unroll
      for (int reg = 0; reg < 4; ++reg) {
        int row = mi * 16 + q * 4 + reg;
        #pragma unroll
        for (int ni = 0; ni < 4; ++ni)
          sA[row * DIM + nb + ni * 16 + lm] = f2bf(acc[mi][ni][reg] + bias[ni]);
      }
    __syncthreads();

    // bulk copy LDS -> msg: 8 iters x 256 threads x 16B = 32 KB linear
    unsigned short* mbase = mdir + (size_t)(beg + tile0) * DIM;
    #pragma unroll
    for (int it = 0; it < 8; ++it) {
      int elem = it * 2048 + tid * 8;
      if ((elem >> 8) < rows_valid) {
        uint4 v = *reinterpret_cast<const uint4*>(sA + elem);
        *reinterpret_cast<uint4*>(mbase + elem) = v;
      }
    }
    __syncthreads();
  }
}

// ---- phase 2: CSR gather-sum of both directions, single out RMW ----------

__global__ void reduce_both_kernel(const unsigned short* __restrict__ msg,
                                   const int* __restrict__ rp,
                                   const int* __restrict__ colf,
                                   const int* __restrict__ colr,
                                   float* __restrict__ out) {
  int n = blockIdx.x, t = threadIdx.x;
  int b0 = rp[n], e0 = rp[n + 1];
  int b1 = rp[(N_NODES + 1) + n], e1 = rp[(N_NODES + 1) + n + 1];
  if (e0 <= b0 && e1 <= b1) return;
  float acc = 0.f;
  for (int j = b0; j < e0; ++j) {
    int row = colf[j];
    unsigned int u = msg[(size_t)row * DIM + t];
    union { unsigned int u; float f; } c; c.u = u << 16;
    acc += c.f;
  }
  for (int j = b1; j < e1; ++j) {
    int row = colr[j];
    unsigned int u = msg[(size_t)(N_EDGES + row) * DIM + t];
    union { unsigned int u; float f; } c; c.u = u << 16;
    acc += c.f;
  }
  out[(size_t)n * DIM + t] += acc;
}

// ---- fallback: single-phase atomic scatter (if ws too small) -------------

__global__ void edge_gemm_atomic_kernel(const unsigned short* __restrict__ xbf,
                                        const unsigned short* __restrict__ wt,
                                        const float* __restrict__ b_fwd,
                                        const float* __restrict__ b_rev,
                                        const int* __restrict__ perm,
                                        const int* __restrict__ rel_start,
                                        const int* __restrict__ dep,
                                        const int* __restrict__ gov,
                                        float* __restrict__ out) {
  const int bucket = blockIdx.y;
  const int r = bucket % N_REL;
  const bool fwd = bucket < N_REL;
  const int beg = rel_start[r];
  const int cnt = rel_start[r + 1] - beg;
  const int ntiles = (cnt + 63) >> 6;

  const int tid = threadIdx.x;
  const int wave = tid >> 6, lane = tid & 63;
  const int lm = lane & 15, q = lane >> 4;
  const int nb = wave * 64;

  __shared__ int s_src[64], s_dst[64];

  const unsigned short* wr[4];
  #pragma unroll
  for (int ni = 0; ni < 4; ++ni)
    wr[ni] = wt + (size_t)bucket * DIM * DIM + (size_t)(nb + ni * 16 + lm) * DIM + q * 8;

  const float* bptr = (fwd ? b_fwd : b_rev) + r * DIM;
  float bias[4];
  #pragma unroll
  for (int ni = 0; ni < 4; ++ni) bias[ni] = bptr[nb + ni * 16 + lm];

  for (int t = blockIdx.x; t < ntiles; t += gridDim.x) {
    const int tile0 = t << 6;
    const int rows_valid = min(64, cnt - tile0);

    if (tid < 64) {
      int s = 0, d = -1;
      if (tid < rows_valid) {
        int e = perm[beg + tile0 + tid];
        int gv = gov[e], dp = dep[e];
        s = fwd ? gv : dp;
        d = fwd ? dp : gv;
      }
      s_src[tid] = s;
      s_dst[tid] = d;
    }
    __syncthreads();

    const unsigned short* xr[4];
    #pragma unroll
    for (int mi = 0; mi < 4; ++mi)
      xr[mi] = xbf + (size_t)s_src[mi * 16 + lm] * DIM + q * 8;

    f32x4 acc[4][4];
    #pragma unroll
    for (int mi = 0; mi < 4; ++mi)
      #pragma unroll
      for (int ni = 0; ni < 4; ++ni)
        acc[mi][ni] = (f32x4){0.f, 0.f, 0.f, 0.f};

    #pragma unroll
    for (int k0 = 0; k0 < DIM; k0 += 32) {
      bf16x8 a[4], b[4];
      #pragma unroll
      for (int mi = 0; mi < 4; ++mi) a[mi] = *reinterpret_cast<const bf16x8*>(xr[mi] + k0);
      #pragma unroll
      for (int ni = 0; ni < 4; ++ni) b[ni] = *reinterpret_cast<const bf16x8*>(wr[ni] + k0);
      #pragma unroll
      for (int mi = 0; mi < 4; ++mi)
        #pragma unroll
        for (int ni = 0; ni < 4; ++ni)
          acc[mi][ni] = __builtin_amdgcn_mfma_f32_16x16x32_bf16(a[mi], b[ni], acc[mi][ni], 0, 0, 0);
    }

    #pragma unroll
    for (int mi = 0; mi < 4; ++mi) {
      #pragma unroll
      for (int reg = 0; reg < 4; ++reg) {
        int row = mi * 16 + q * 4 + reg;
        if (row < rows_valid) {
          int dst = s_dst[row];
          float* op = out + (size_t)dst * DIM + nb + lm;
          #pragma unroll
          for (int ni = 0; ni < 4; ++ni)
            atomicAdd(op + ni * 16, acc[mi][ni][reg] + bias[ni]);
        }
      }
    }
    __syncthreads();
  }
}

// ---- launch --------------------------------------------------------------

extern "C" void kernel_launch(void* const* d_in, const int* in_sizes, int n_in,
                              void* d_out, int out_size, void* d_ws, size_t ws_size,
                              hipStream_t stream) {
  const float* x      = (const float*)d_in[0];
  const float* W_self = (const float*)d_in[1];
  const float* b_self = (const float*)d_in[2];
  const float* W_fwd  = (const float*)d_in[3];
  const float* b_fwd  = (const float*)d_in[4];
  const float* W_rev  = (const float*)d_in[5];
  const float* b_rev  = (const float*)d_in[6];
  const int* dep = (const int*)d_in[7];
  const int* rel = (const int*)d_in[8];
  const int* gov = (const int*)d_in[9];
  float* out = (float*)d_out;

  char* base = (char*)d_ws;
  size_t off = 0;
  auto alloc = [&](size_t bytes) -> char* {
    char* p = base + off;
    off = (off + bytes + 15) & ~(size_t)15;
    return p;
  };

  unsigned short* xbf = (unsigned short*)alloc((size_t)N_NODES * DIM * 2);   // 15.36 MB
  unsigned short* wt  = (unsigned short*)alloc((size_t)21 * DIM * DIM * 2);  // 2.75 MB
  int* perm          = (int*)alloc((size_t)N_EDGES * 4);
  int* rel_start     = (int*)alloc(16 * 4);
  int* block_counts  = (int*)alloc(SORT_BLOCKS * N_REL * 4);
  int* block_offset  = (int*)alloc(SORT_BLOCKS * N_REL * 4);
  // two-phase extras
  int* cnt       = (int*)alloc((size_t)2 * N_NODES * 4);
  int* tmp       = (int*)alloc((size_t)2 * N_NODES * 4);
  int* sums      = (int*)alloc((size_t)2 * SCAN_BLOCKS * 4);
  int* chunk_off = (int*)alloc((size_t)2 * SCAN_BLOCKS * 4);
  int* rp        = (int*)alloc((size_t)2 * (N_NODES + 1) * 4);
  int* cursor    = (int*)alloc((size_t)2 * N_NODES * 4);
  int* colf      = (int*)alloc((size_t)N_EDGES * 4);
  int* colr      = (int*)alloc((size_t)N_EDGES * 4);
  unsigned short* msg = (unsigned short*)alloc((size_t)2 * N_EDGES * DIM * 2);  // 153.6 MB
  const bool two_phase = (off <= ws_size);

  conv_x_kernel<<<N_NODES * DIM / 4 / 256, 256, 0, stream>>>(x, xbf);
  conv_w_kernel<<<21 * DIM * DIM / 256, 256, 0, stream>>>(W_fwd, W_rev, W_self, wt);
  blockhist_kernel<<<SORT_BLOCKS, 256, 0, stream>>>(rel, block_counts);
  scan_rel_kernel<<<1, 64, 0, stream>>>(block_counts, rel_start, block_offset);
  scatter2_kernel<<<SORT_BLOCKS, 256, 0, stream>>>(rel, block_offset, perm);
  // self GEMM first: plain stores initialize all of out (stream-ordered
  // ahead of any accumulation)
  self_gemm_kernel<<<120, 256, 0, stream>>>(
      xbf, wt + (size_t)20 * DIM * DIM, b_self, out);

  if (two_phase) {
    zero_cnt_kernel<<<(2 * N_NODES + 255) / 256, 256, 0, stream>>>(cnt, 2 * N_NODES);
    hist_dst_kernel<<<(N_EDGES + 255) / 256, 256, 0, stream>>>(dep, gov, cnt);
    scanA_kernel<<<dim3(SCAN_BLOCKS, 2), SCAN_CHUNK, 0, stream>>>(cnt, tmp, sums);
    scanB_kernel<<<2, 128, 0, stream>>>(sums, chunk_off, rp);
    scanC_kernel<<<dim3(SCAN_BLOCKS, 2), SCAN_CHUNK, 0, stream>>>(tmp, chunk_off, rp, cursor);
    colidx_kernel<<<(N_EDGES + 255) / 256, 256, 0, stream>>>(perm, dep, gov, cursor, colf, colr);

    // both directions in one launch; 48 blocks.x -> ~5 tiles/block so the
    // hoisted W registers amortize
    edge_gemm_p1_kernel<<<dim3(48, 2 * N_REL), 256, 0, stream>>>(
        xbf, wt, b_fwd, b_rev, perm, rel_start, dep, gov, msg);
    reduce_both_kernel<<<N_NODES, 256, 0, stream>>>(msg, rp, colf, colr, out);
  } else {
    edge_gemm_atomic_kernel<<<dim3(260, 20), 256, 0, stream>>>(
        xbf, wt, b_fwd, b_rev, perm, rel_start, dep, gov, out);
  }
}

// Round 8
// 303.042 us; speedup vs baseline: 3.2224x; 1.0859x over previous
//
#include <hip/hip_runtime.h>

#define N_NODES 30000
#define N_EDGES 150000
#define N_REL 10
#define DIM 256

#define SORT_BLOCKS 120
#define SORT_CHUNK ((N_EDGES + SORT_BLOCKS - 1) / SORT_BLOCKS)  // 1250

#define SCAN_CHUNK 256
#define SCAN_BLOCKS ((N_NODES + SCAN_CHUNK - 1) / SCAN_CHUNK)   // 118

// LDS A-tile row stride: 280 shorts = 560 B (16B-aligned, breaks pow2 banks)
#define A_STRIDE 280

typedef __attribute__((ext_vector_type(8))) short bf16x8;
typedef __attribute__((ext_vector_type(4))) float f32x4;

__device__ __forceinline__ unsigned short f2bf(float f) {
  union { float f; unsigned int u; } v; v.f = f;
  unsigned int u = v.u;
  unsigned int r = u + 0x7fffu + ((u >> 16) & 1u);  // RNE
  return (unsigned short)(r >> 16);
}

// ---- preprocessing -------------------------------------------------------

__global__ void conv_x_kernel(const float* __restrict__ x,
                              unsigned short* __restrict__ xbf) {
  int idx = blockIdx.x * blockDim.x + threadIdx.x;  // one float4 each, exact grid
  float4 v = reinterpret_cast<const float4*>(x)[idx];
  ushort4 o;
  o.x = f2bf(v.x); o.y = f2bf(v.y); o.z = f2bf(v.z); o.w = f2bf(v.w);
  reinterpret_cast<ushort4*>(xbf)[idx] = o;
}

// wt[b][o][i] = W_b[i][o] (bf16), buckets: 0..9 fwd, 10..19 rev, 20 self
__global__ void conv_w_kernel(const float* __restrict__ Wf,
                              const float* __restrict__ Wr,
                              const float* __restrict__ Ws,
                              unsigned short* __restrict__ wt) {
  int idx = blockIdx.x * blockDim.x + threadIdx.x;  // exact grid 21*65536
  int b = idx >> 16;
  int t = idx & 65535;
  int o = t >> 8, i = t & 255;
  const float* src = (b < N_REL) ? (Wf + (size_t)b * 65536)
                   : (b < 2 * N_REL) ? (Wr + (size_t)(b - N_REL) * 65536)
                   : Ws;
  wt[idx] = f2bf(src[i * 256 + o]);
}

__global__ void zero_cnt_kernel(int* __restrict__ cnt, int n) {
  int i = blockIdx.x * blockDim.x + threadIdx.x;
  if (i < n) cnt[i] = 0;
}

// one edge pass: per-block rel histogram (LDS) + global dst histograms
__global__ void hist_all_kernel(const int* __restrict__ rel,
                                const int* __restrict__ dep,
                                const int* __restrict__ gov,
                                int* __restrict__ block_counts,
                                int* __restrict__ cnt) {
  __shared__ int h[N_REL];
  if (threadIdx.x < N_REL) h[threadIdx.x] = 0;
  __syncthreads();
  int beg = blockIdx.x * SORT_CHUNK;
  int end = min(beg + SORT_CHUNK, N_EDGES);
  for (int e = beg + threadIdx.x; e < end; e += blockDim.x) {
    atomicAdd(&h[rel[e]], 1);
    atomicAdd(&cnt[dep[e]], 1);             // 30k bins: low contention
    atomicAdd(&cnt[N_NODES + gov[e]], 1);
  }
  __syncthreads();
  if (threadIdx.x < N_REL)
    block_counts[blockIdx.x * N_REL + threadIdx.x] = h[threadIdx.x];
}

__global__ void scan_rel_kernel(const int* __restrict__ block_counts,
                                int* __restrict__ rel_start,
                                int* __restrict__ block_offset) {
  __shared__ int tot[N_REL];
  int r = threadIdx.x;
  if (r < N_REL) {
    int s = 0;
    for (int b = 0; b < SORT_BLOCKS; ++b) s += block_counts[b * N_REL + r];
    tot[r] = s;
  }
  __syncthreads();
  if (threadIdx.x == 0) {
    int s = 0;
    for (int i = 0; i < N_REL; ++i) { rel_start[i] = s; s += tot[i]; }
    rel_start[N_REL] = s;
  }
  __syncthreads();
  if (r < N_REL) {
    int run = rel_start[r];
    for (int b = 0; b < SORT_BLOCKS; ++b) {
      block_offset[b * N_REL + r] = run;
      run += block_counts[b * N_REL + r];
    }
  }
}

__global__ void scanA_kernel(const int* __restrict__ cnt,
                             int* __restrict__ tmp, int* __restrict__ sums) {
  __shared__ int s[SCAN_CHUNK];
  int d = blockIdx.y, b = blockIdx.x, t = threadIdx.x;
  int i = b * SCAN_CHUNK + t;
  int v = (i < N_NODES) ? cnt[d * N_NODES + i] : 0;
  s[t] = v;
  __syncthreads();
  for (int off = 1; off < SCAN_CHUNK; off <<= 1) {
    int add = (t >= off) ? s[t - off] : 0;
    __syncthreads();
    s[t] += add;
    __syncthreads();
  }
  if (i < N_NODES) tmp[d * N_NODES + i] = s[t] - v;  // exclusive
  if (t == SCAN_CHUNK - 1) sums[d * SCAN_BLOCKS + b] = s[t];
}

__global__ void scanB_kernel(const int* __restrict__ sums,
                             int* __restrict__ chunk_off, int* __restrict__ rp) {
  __shared__ int s[128];
  int d = blockIdx.x, t = threadIdx.x;
  int v = (t < SCAN_BLOCKS) ? sums[d * SCAN_BLOCKS + t] : 0;
  s[t] = v;
  __syncthreads();
  for (int off = 1; off < 128; off <<= 1) {
    int add = (t >= off) ? s[t - off] : 0;
    __syncthreads();
    s[t] += add;
    __syncthreads();
  }
  if (t < SCAN_BLOCKS) chunk_off[d * SCAN_BLOCKS + t] = s[t] - v;
  if (t == 127) rp[d * (N_NODES + 1) + N_NODES] = s[127];
}

__global__ void scanC_kernel(const int* __restrict__ tmp,
                             const int* __restrict__ chunk_off,
                             int* __restrict__ rp, int* __restrict__ cursor) {
  int d = blockIdx.y;
  int i = blockIdx.x * SCAN_CHUNK + threadIdx.x;
  if (i < N_NODES) {
    int v = tmp[d * N_NODES + i] + chunk_off[d * SCAN_BLOCKS + blockIdx.x];
    rp[d * (N_NODES + 1) + i] = v;
    cursor[d * N_NODES + i] = v;
  }
}

// rel-scatter producing perm AND the dst-keyed col lists in one pass
__global__ void scatter_all_kernel(const int* __restrict__ rel,
                                   const int* __restrict__ dep,
                                   const int* __restrict__ gov,
                                   const int* __restrict__ block_offset,
                                   int* __restrict__ cursor,
                                   int* __restrict__ perm,
                                   int* __restrict__ colf,
                                   int* __restrict__ colr) {
  __shared__ int cur[N_REL];
  if (threadIdx.x < N_REL)
    cur[threadIdx.x] = block_offset[blockIdx.x * N_REL + threadIdx.x];
  __syncthreads();
  int beg = blockIdx.x * SORT_CHUNK;
  int end = min(beg + SORT_CHUNK, N_EDGES);
  for (int e = beg + threadIdx.x; e < end; e += blockDim.x) {
    int pos = atomicAdd(&cur[rel[e]], 1);  // LDS atomic, cheap
    perm[pos] = e;
    colf[atomicAdd(&cursor[dep[e]], 1)] = pos;             // fwd msg pos -> dep
    colr[atomicAdd(&cursor[N_NODES + gov[e]], 1)] = pos;   // rev msg pos -> gov
  }
}

// ---- self GEMM: out = x @ W_self + b_self (plain stores, runs first) -----

__global__ __launch_bounds__(256, 2)
void self_gemm_kernel(const unsigned short* __restrict__ xbf,
                      const unsigned short* __restrict__ wt_self,
                      const float* __restrict__ b_self,
                      float* __restrict__ out) {
  const int tid = threadIdx.x;
  const int wave = tid >> 6, lane = tid & 63;
  const int lm = lane & 15, q = lane >> 4;
  const int nb = wave * 64;

  // hoisted, loop-invariant W fragments: 8 k-steps x 4 ni = 128 VGPRs
  bf16x8 wf[8][4];
  #pragma unroll
  for (int kk = 0; kk < 8; ++kk)
    #pragma unroll
    for (int ni = 0; ni < 4; ++ni)
      wf[kk][ni] = *reinterpret_cast<const bf16x8*>(
          wt_self + (size_t)(nb + ni * 16 + lm) * DIM + kk * 32 + q * 8);

  float bias[4];
  #pragma unroll
  for (int ni = 0; ni < 4; ++ni) bias[ni] = b_self[nb + ni * 16 + lm];

  const int ntiles = (N_NODES + 63) / 64;
  for (int t = blockIdx.x; t < ntiles; t += gridDim.x) {
    const int row0 = t * 64;
    const unsigned short* xr[4];
    #pragma unroll
    for (int mi = 0; mi < 4; ++mi) {
      int r = row0 + mi * 16 + lm;
      int rc = r < N_NODES ? r : N_NODES - 1;
      xr[mi] = xbf + (size_t)rc * DIM + q * 8;
    }

    f32x4 acc[4][4];
    #pragma unroll
    for (int mi = 0; mi < 4; ++mi)
      #pragma unroll
      for (int ni = 0; ni < 4; ++ni)
        acc[mi][ni] = (f32x4){0.f, 0.f, 0.f, 0.f};

    #pragma unroll
    for (int kk = 0; kk < 8; ++kk) {
      bf16x8 a[4];
      #pragma unroll
      for (int mi = 0; mi < 4; ++mi)
        a[mi] = *reinterpret_cast<const bf16x8*>(xr[mi] + kk * 32);
      #pragma unroll
      for (int mi = 0; mi < 4; ++mi)
        #pragma unroll
        for (int ni = 0; ni < 4; ++ni)
          acc[mi][ni] = __builtin_amdgcn_mfma_f32_16x16x32_bf16(a[mi], wf[kk][ni], acc[mi][ni], 0, 0, 0);
    }

    #pragma unroll
    for (int mi = 0; mi < 4; ++mi) {
      #pragma unroll
      for (int reg = 0; reg < 4; ++reg) {
        int row = row0 + mi * 16 + q * 4 + reg;  // C/D: row = quad*4 + reg
        if (row < N_NODES) {
          #pragma unroll
          for (int ni = 0; ni < 4; ++ni)
            out[(size_t)row * DIM + nb + ni * 16 + lm] = acc[mi][ni][reg] + bias[ni];
        }
      }
    }
  }
}

// ---- phase 1: both directions, rel-bucketed GEMM, hoisted W --------------

__global__ __launch_bounds__(256, 2)
void edge_gemm_p1_kernel(const unsigned short* __restrict__ xbf,
                         const unsigned short* __restrict__ wt,
                         const float* __restrict__ b_fwd,
                         const float* __restrict__ b_rev,
                         const int* __restrict__ perm,
                         const int* __restrict__ rel_start,
                         const int* __restrict__ dep,
                         const int* __restrict__ gov,
                         unsigned short* __restrict__ msg) {
  const int bkt = blockIdx.y;
  const int r = bkt % N_REL;
  const bool fwd = bkt < N_REL;
  const int* src_idx = fwd ? gov : dep;
  unsigned short* mdir = msg + (fwd ? 0 : (size_t)N_EDGES * DIM);
  const int beg = rel_start[r];
  const int cnt = rel_start[r + 1] - beg;
  const int ntiles = (cnt + 63) >> 6;

  const int tid = threadIdx.x;
  const int wave = tid >> 6, lane = tid & 63;
  const int lm = lane & 15, q = lane >> 4;
  const int nb = wave * 64;

  __shared__ int s_src[64];
  __shared__ unsigned short sA[64 * A_STRIDE];  // 35840 B; reused by epilogue

  // hoisted, tile-invariant W fragments (128 VGPRs, amortized over ~5 tiles)
  bf16x8 wf[8][4];
  const unsigned short* wbase = wt + (size_t)bkt * DIM * DIM;
  #pragma unroll
  for (int kk = 0; kk < 8; ++kk)
    #pragma unroll
    for (int ni = 0; ni < 4; ++ni)
      wf[kk][ni] = *reinterpret_cast<const bf16x8*>(
          wbase + (size_t)(nb + ni * 16 + lm) * DIM + kk * 32 + q * 8);

  const float* bptr = (fwd ? b_fwd : b_rev) + r * DIM;
  float bias[4];
  #pragma unroll
  for (int ni = 0; ni < 4; ++ni) bias[ni] = bptr[nb + ni * 16 + lm];

  for (int t = blockIdx.x; t < ntiles; t += gridDim.x) {
    const int tile0 = t << 6;
    const int rows_valid = min(64, cnt - tile0);

    if (tid < 64) {
      int s = 0;
      if (tid < rows_valid) s = src_idx[perm[beg + tile0 + tid]];
      s_src[tid] = s;
    }
    __syncthreads();

    // stage 64 gathered x rows into LDS (each row fetched exactly once)
    {
      int half = lane >> 5;        // 0 or 1
      int lcol = lane & 31;        // 16B chunk index within row
      #pragma unroll
      for (int i = 0; i < 8; ++i) {
        int row = wave * 16 + i * 2 + half;
        uint4 v = *reinterpret_cast<const uint4*>(
            xbf + (size_t)s_src[row] * DIM + lcol * 8);
        *reinterpret_cast<uint4*>(sA + row * A_STRIDE + lcol * 8) = v;
      }
    }
    __syncthreads();

    f32x4 acc[4][4];
    #pragma unroll
    for (int mi = 0; mi < 4; ++mi)
      #pragma unroll
      for (int ni = 0; ni < 4; ++ni)
        acc[mi][ni] = (f32x4){0.f, 0.f, 0.f, 0.f};

    // pure LDS-read + MFMA k-loop (W is in registers)
    #pragma unroll
    for (int kk = 0; kk < 8; ++kk) {
      bf16x8 a[4];
      #pragma unroll
      for (int mi = 0; mi < 4; ++mi)
        a[mi] = *reinterpret_cast<const bf16x8*>(
            sA + (mi * 16 + lm) * A_STRIDE + kk * 32 + q * 8);
      #pragma unroll
      for (int mi = 0; mi < 4; ++mi)
        #pragma unroll
        for (int ni = 0; ni < 4; ++ni)
          acc[mi][ni] = __builtin_amdgcn_mfma_f32_16x16x32_bf16(a[mi], wf[kk][ni], acc[mi][ni], 0, 0, 0);
    }
    __syncthreads();  // k-loop done; sA free for epilogue transpose

    // transpose acc to natural [row][col] bf16 layout in LDS
    #pragma unroll
    for (int mi = 0; mi < 4; ++mi)
      #pragma unroll
      for (int reg = 0; reg < 4; ++reg) {
        int row = mi * 16 + q * 4 + reg;
        #pragma unroll
        for (int ni = 0; ni < 4; ++ni)
          sA[row * DIM + nb + ni * 16 + lm] = f2bf(acc[mi][ni][reg] + bias[ni]);
      }
    __syncthreads();

    // bulk copy LDS -> msg: 8 iters x 256 threads x 16B = 32 KB linear
    unsigned short* mbase = mdir + (size_t)(beg + tile0) * DIM;
    #pragma unroll
    for (int it = 0; it < 8; ++it) {
      int elem = it * 2048 + tid * 8;
      if ((elem >> 8) < rows_valid) {
        uint4 v = *reinterpret_cast<const uint4*>(sA + elem);
        *reinterpret_cast<uint4*>(mbase + elem) = v;
      }
    }
    __syncthreads();
  }
}

// ---- phase 2: CSR gather-sum, 4-row parallel, uint2 loads ----------------

__global__ void reduce_both_kernel(const unsigned short* __restrict__ msg,
                                   const int* __restrict__ rp,
                                   const int* __restrict__ colf,
                                   const int* __restrict__ colr,
                                   float* __restrict__ out) {
  const int n = blockIdx.x, t = threadIdx.x;
  const int g = t >> 6, lane = t & 63;
  const int b0 = rp[n], e0 = rp[n + 1];
  const int b1 = rp[(N_NODES + 1) + n], e1 = rp[(N_NODES + 1) + n + 1];
  if (e0 <= b0 && e1 <= b1) return;

  float a0 = 0.f, a1 = 0.f, a2 = 0.f, a3 = 0.f;
  // group g handles rows b+g, b+g+4, ... ; each thread covers 4 columns (8B)
  for (int j = b0 + g; j < e0; j += 4) {
    int row = colf[j];
    uint2 v = *reinterpret_cast<const uint2*>(msg + (size_t)row * DIM + lane * 4);
    union { unsigned int u; float f; } c;
    c.u = v.x << 16;          a0 += c.f;
    c.u = v.x & 0xffff0000u;  a1 += c.f;
    c.u = v.y << 16;          a2 += c.f;
    c.u = v.y & 0xffff0000u;  a3 += c.f;
  }
  for (int j = b1 + g; j < e1; j += 4) {
    int row = colr[j];
    uint2 v = *reinterpret_cast<const uint2*>(
        msg + (size_t)(N_EDGES + row) * DIM + lane * 4);
    union { unsigned int u; float f; } c;
    c.u = v.x << 16;          a0 += c.f;
    c.u = v.x & 0xffff0000u;  a1 += c.f;
    c.u = v.y << 16;          a2 += c.f;
    c.u = v.y & 0xffff0000u;  a3 += c.f;
  }

  __shared__ float part[4][DIM];
  part[g][lane * 4 + 0] = a0;
  part[g][lane * 4 + 1] = a1;
  part[g][lane * 4 + 2] = a2;
  part[g][lane * 4 + 3] = a3;
  __syncthreads();
  float s = part[0][t] + part[1][t] + part[2][t] + part[3][t];
  out[(size_t)n * DIM + t] += s;
}

// ---- fallback: single-phase atomic scatter (if ws too small) -------------

__global__ void edge_gemm_atomic_kernel(const unsigned short* __restrict__ xbf,
                                        const unsigned short* __restrict__ wt,
                                        const float* __restrict__ b_fwd,
                                        const float* __restrict__ b_rev,
                                        const int* __restrict__ perm,
                                        const int* __restrict__ rel_start,
                                        const int* __restrict__ dep,
                                        const int* __restrict__ gov,
                                        float* __restrict__ out) {
  const int bucket = blockIdx.y;
  const int r = bucket % N_REL;
  const bool fwd = bucket < N_REL;
  const int beg = rel_start[r];
  const int cnt = rel_start[r + 1] - beg;
  const int ntiles = (cnt + 63) >> 6;

  const int tid = threadIdx.x;
  const int wave = tid >> 6, lane = tid & 63;
  const int lm = lane & 15, q = lane >> 4;
  const int nb = wave * 64;

  __shared__ int s_src[64], s_dst[64];

  const unsigned short* wr[4];
  #pragma unroll
  for (int ni = 0; ni < 4; ++ni)
    wr[ni] = wt + (size_t)bucket * DIM * DIM + (size_t)(nb + ni * 16 + lm) * DIM + q * 8;

  const float* bptr = (fwd ? b_fwd : b_rev) + r * DIM;
  float bias[4];
  #pragma unroll
  for (int ni = 0; ni < 4; ++ni) bias[ni] = bptr[nb + ni * 16 + lm];

  for (int t = blockIdx.x; t < ntiles; t += gridDim.x) {
    const int tile0 = t << 6;
    const int rows_valid = min(64, cnt - tile0);

    if (tid < 64) {
      int s = 0, d = -1;
      if (tid < rows_valid) {
        int e = perm[beg + tile0 + tid];
        int gv = gov[e], dp = dep[e];
        s = fwd ? gv : dp;
        d = fwd ? dp : gv;
      }
      s_src[tid] = s;
      s_dst[tid] = d;
    }
    __syncthreads();

    const unsigned short* xr[4];
    #pragma unroll
    for (int mi = 0; mi < 4; ++mi)
      xr[mi] = xbf + (size_t)s_src[mi * 16 + lm] * DIM + q * 8;

    f32x4 acc[4][4];
    #pragma unroll
    for (int mi = 0; mi < 4; ++mi)
      #pragma unroll
      for (int ni = 0; ni < 4; ++ni)
        acc[mi][ni] = (f32x4){0.f, 0.f, 0.f, 0.f};

    #pragma unroll
    for (int k0 = 0; k0 < DIM; k0 += 32) {
      bf16x8 a[4], b[4];
      #pragma unroll
      for (int mi = 0; mi < 4; ++mi) a[mi] = *reinterpret_cast<const bf16x8*>(xr[mi] + k0);
      #pragma unroll
      for (int ni = 0; ni < 4; ++ni) b[ni] = *reinterpret_cast<const bf16x8*>(wr[ni] + k0);
      #pragma unroll
      for (int mi = 0; mi < 4; ++mi)
        #pragma unroll
        for (int ni = 0; ni < 4; ++ni)
          acc[mi][ni] = __builtin_amdgcn_mfma_f32_16x16x32_bf16(a[mi], b[ni], acc[mi][ni], 0, 0, 0);
    }

    #pragma unroll
    for (int mi = 0; mi < 4; ++mi) {
      #pragma unroll
      for (int reg = 0; reg < 4; ++reg) {
        int row = mi * 16 + q * 4 + reg;
        if (row < rows_valid) {
          int dst = s_dst[row];
          float* op = out + (size_t)dst * DIM + nb + lm;
          #pragma unroll
          for (int ni = 0; ni < 4; ++ni)
            atomicAdd(op + ni * 16, acc[mi][ni][reg] + bias[ni]);
        }
      }
    }
    __syncthreads();
  }
}

// ---- launch --------------------------------------------------------------

extern "C" void kernel_launch(void* const* d_in, const int* in_sizes, int n_in,
                              void* d_out, int out_size, void* d_ws, size_t ws_size,
                              hipStream_t stream) {
  const float* x      = (const float*)d_in[0];
  const float* W_self = (const float*)d_in[1];
  const float* b_self = (const float*)d_in[2];
  const float* W_fwd  = (const float*)d_in[3];
  const float* b_fwd  = (const float*)d_in[4];
  const float* W_rev  = (const float*)d_in[5];
  const float* b_rev  = (const float*)d_in[6];
  const int* dep = (const int*)d_in[7];
  const int* rel = (const int*)d_in[8];
  const int* gov = (const int*)d_in[9];
  float* out = (float*)d_out;

  char* base = (char*)d_ws;
  size_t off = 0;
  auto alloc = [&](size_t bytes) -> char* {
    char* p = base + off;
    off = (off + bytes + 15) & ~(size_t)15;
    return p;
  };

  unsigned short* xbf = (unsigned short*)alloc((size_t)N_NODES * DIM * 2);   // 15.36 MB
  unsigned short* wt  = (unsigned short*)alloc((size_t)21 * DIM * DIM * 2);  // 2.75 MB
  int* perm          = (int*)alloc((size_t)N_EDGES * 4);
  int* rel_start     = (int*)alloc(16 * 4);
  int* block_counts  = (int*)alloc(SORT_BLOCKS * N_REL * 4);
  int* block_offset  = (int*)alloc(SORT_BLOCKS * N_REL * 4);
  // two-phase extras
  int* cnt       = (int*)alloc((size_t)2 * N_NODES * 4);
  int* tmp       = (int*)alloc((size_t)2 * N_NODES * 4);
  int* sums      = (int*)alloc((size_t)2 * SCAN_BLOCKS * 4);
  int* chunk_off = (int*)alloc((size_t)2 * SCAN_BLOCKS * 4);
  int* rp        = (int*)alloc((size_t)2 * (N_NODES + 1) * 4);
  int* cursor    = (int*)alloc((size_t)2 * N_NODES * 4);
  int* colf      = (int*)alloc((size_t)N_EDGES * 4);
  int* colr      = (int*)alloc((size_t)N_EDGES * 4);
  unsigned short* msg = (unsigned short*)alloc((size_t)2 * N_EDGES * DIM * 2);  // 153.6 MB
  const bool two_phase = (off <= ws_size);

  conv_x_kernel<<<N_NODES * DIM / 4 / 256, 256, 0, stream>>>(x, xbf);
  conv_w_kernel<<<21 * DIM * DIM / 256, 256, 0, stream>>>(W_fwd, W_rev, W_self, wt);

  if (two_phase) {
    zero_cnt_kernel<<<(2 * N_NODES + 255) / 256, 256, 0, stream>>>(cnt, 2 * N_NODES);
    hist_all_kernel<<<SORT_BLOCKS, 256, 0, stream>>>(rel, dep, gov, block_counts, cnt);
    scan_rel_kernel<<<1, 64, 0, stream>>>(block_counts, rel_start, block_offset);
    scanA_kernel<<<dim3(SCAN_BLOCKS, 2), SCAN_CHUNK, 0, stream>>>(cnt, tmp, sums);
    scanB_kernel<<<2, 128, 0, stream>>>(sums, chunk_off, rp);
    scanC_kernel<<<dim3(SCAN_BLOCKS, 2), SCAN_CHUNK, 0, stream>>>(tmp, chunk_off, rp, cursor);
    scatter_all_kernel<<<SORT_BLOCKS, 256, 0, stream>>>(
        rel, dep, gov, block_offset, cursor, perm, colf, colr);

    // self GEMM: plain stores initialize all of out (stream-ordered ahead of
    // the reduce's RMW)
    self_gemm_kernel<<<120, 256, 0, stream>>>(
        xbf, wt + (size_t)20 * DIM * DIM, b_self, out);

    // both directions in one launch; 48 blocks.x -> ~5 tiles/block so the
    // hoisted W registers amortize
    edge_gemm_p1_kernel<<<dim3(48, 2 * N_REL), 256, 0, stream>>>(
        xbf, wt, b_fwd, b_rev, perm, rel_start, dep, gov, msg);
    reduce_both_kernel<<<N_NODES, 256, 0, stream>>>(msg, rp, colf, colr, out);
  } else {
    zero_cnt_kernel<<<(2 * N_NODES + 255) / 256, 256, 0, stream>>>(cnt, 2 * N_NODES);
    hist_all_kernel<<<SORT_BLOCKS, 256, 0, stream>>>(rel, dep, gov, block_counts, cnt);
    scan_rel_kernel<<<1, 64, 0, stream>>>(block_counts, rel_start, block_offset);
    scanA_kernel<<<dim3(SCAN_BLOCKS, 2), SCAN_CHUNK, 0, stream>>>(cnt, tmp, sums);
    scanB_kernel<<<2, 128, 0, stream>>>(sums, chunk_off, rp);
    scanC_kernel<<<dim3(SCAN_BLOCKS, 2), SCAN_CHUNK, 0, stream>>>(tmp, chunk_off, rp, cursor);
    scatter_all_kernel<<<SORT_BLOCKS, 256, 0, stream>>>(
        rel, dep, gov, block_offset, cursor, perm, colf, colr);
    self_gemm_kernel<<<120, 256, 0, stream>>>(
        xbf, wt + (size_t)20 * DIM * DIM, b_self, out);
    edge_gemm_atomic_kernel<<<dim3(260, 20), 256, 0, stream>>>(
        xbf, wt, b_fwd, b_rev, perm, rel_start, dep, gov, out);
  }
}

// Round 9
// 280.870 us; speedup vs baseline: 3.4768x; 1.0789x over previous
//
#include <hip/hip_runtime.h>

#define N_NODES 30000
#define N_EDGES 150000
#define N_REL 10
#define DIM 256

#define SORT_BLOCKS 120
#define SORT_CHUNK ((N_EDGES + SORT_BLOCKS - 1) / SORT_BLOCKS)  // 1250

#define SCAN_CHUNK 256
#define SCAN_BLOCKS ((N_NODES + SCAN_CHUNK - 1) / SCAN_CHUNK)   // 118

// LDS A-tile row stride: 280 shorts = 560 B (16B-aligned, breaks pow2 banks)
#define A_STRIDE 280

// prep kernel block ranges
#define PREP_XB 7500   // conv_x: 30000*256/4/256
#define PREP_WB 5376   // conv_w: 21*65536/256
#define PREP_ZB 235    // zero cnt: (60000+255)/256

typedef __attribute__((ext_vector_type(8))) short bf16x8;
typedef __attribute__((ext_vector_type(4))) float f32x4;

__device__ __forceinline__ unsigned short f2bf(float f) {
  union { float f; unsigned int u; } v; v.f = f;
  unsigned int u = v.u;
  unsigned int r = u + 0x7fffu + ((u >> 16) & 1u);  // RNE
  return (unsigned short)(r >> 16);
}

// ---- fused preprocessing: x->bf16, W->bf16 transposed, zero cnt ----------

__global__ void prep_kernel(const float* __restrict__ x,
                            const float* __restrict__ Wf,
                            const float* __restrict__ Wr,
                            const float* __restrict__ Ws,
                            unsigned short* __restrict__ xbf,
                            unsigned short* __restrict__ wt,
                            int* __restrict__ cnt) {
  int b = blockIdx.x;
  if (b < PREP_XB) {
    int idx = b * 256 + threadIdx.x;  // one float4 each, exact
    float4 v = reinterpret_cast<const float4*>(x)[idx];
    ushort4 o;
    o.x = f2bf(v.x); o.y = f2bf(v.y); o.z = f2bf(v.z); o.w = f2bf(v.w);
    reinterpret_cast<ushort4*>(xbf)[idx] = o;
  } else if (b < PREP_XB + PREP_WB) {
    int idx = (b - PREP_XB) * 256 + threadIdx.x;  // wt[b][o][i] = W_b[i][o]
    int bb = idx >> 16;
    int t = idx & 65535;
    int o = t >> 8, i = t & 255;
    const float* src = (bb < N_REL) ? (Wf + (size_t)bb * 65536)
                     : (bb < 2 * N_REL) ? (Wr + (size_t)(bb - N_REL) * 65536)
                     : Ws;
    wt[idx] = f2bf(src[i * 256 + o]);
  } else {
    int i = (b - PREP_XB - PREP_WB) * 256 + threadIdx.x;
    if (i < 2 * N_NODES) cnt[i] = 0;
  }
}

// one edge pass: per-block rel histogram (LDS) + global dst histograms
__global__ void hist_all_kernel(const int* __restrict__ rel,
                                const int* __restrict__ dep,
                                const int* __restrict__ gov,
                                int* __restrict__ block_counts,
                                int* __restrict__ cnt) {
  __shared__ int h[N_REL];
  if (threadIdx.x < N_REL) h[threadIdx.x] = 0;
  __syncthreads();
  int beg = blockIdx.x * SORT_CHUNK;
  int end = min(beg + SORT_CHUNK, N_EDGES);
  for (int e = beg + threadIdx.x; e < end; e += blockDim.x) {
    atomicAdd(&h[rel[e]], 1);
    atomicAdd(&cnt[dep[e]], 1);             // 30k bins: low contention
    atomicAdd(&cnt[N_NODES + gov[e]], 1);
  }
  __syncthreads();
  if (threadIdx.x < N_REL)
    block_counts[blockIdx.x * N_REL + threadIdx.x] = h[threadIdx.x];
}

__global__ void scan_rel_kernel(const int* __restrict__ block_counts,
                                int* __restrict__ rel_start,
                                int* __restrict__ block_offset) {
  __shared__ int tot[N_REL];
  int r = threadIdx.x;
  if (r < N_REL) {
    int s = 0;
    for (int b = 0; b < SORT_BLOCKS; ++b) s += block_counts[b * N_REL + r];
    tot[r] = s;
  }
  __syncthreads();
  if (threadIdx.x == 0) {
    int s = 0;
    for (int i = 0; i < N_REL; ++i) { rel_start[i] = s; s += tot[i]; }
    rel_start[N_REL] = s;
  }
  __syncthreads();
  if (r < N_REL) {
    int run = rel_start[r];
    for (int b = 0; b < SORT_BLOCKS; ++b) {
      block_offset[b * N_REL + r] = run;
      run += block_counts[b * N_REL + r];
    }
  }
}

__global__ void scanA_kernel(const int* __restrict__ cnt,
                             int* __restrict__ tmp, int* __restrict__ sums) {
  __shared__ int s[SCAN_CHUNK];
  int d = blockIdx.y, b = blockIdx.x, t = threadIdx.x;
  int i = b * SCAN_CHUNK + t;
  int v = (i < N_NODES) ? cnt[d * N_NODES + i] : 0;
  s[t] = v;
  __syncthreads();
  for (int off = 1; off < SCAN_CHUNK; off <<= 1) {
    int add = (t >= off) ? s[t - off] : 0;
    __syncthreads();
    s[t] += add;
    __syncthreads();
  }
  if (i < N_NODES) tmp[d * N_NODES + i] = s[t] - v;  // exclusive
  if (t == SCAN_CHUNK - 1) sums[d * SCAN_BLOCKS + b] = s[t];
}

__global__ void scanB_kernel(const int* __restrict__ sums,
                             int* __restrict__ chunk_off, int* __restrict__ rp) {
  __shared__ int s[128];
  int d = blockIdx.x, t = threadIdx.x;
  int v = (t < SCAN_BLOCKS) ? sums[d * SCAN_BLOCKS + t] : 0;
  s[t] = v;
  __syncthreads();
  for (int off = 1; off < 128; off <<= 1) {
    int add = (t >= off) ? s[t - off] : 0;
    __syncthreads();
    s[t] += add;
    __syncthreads();
  }
  if (t < SCAN_BLOCKS) chunk_off[d * SCAN_BLOCKS + t] = s[t] - v;
  if (t == 127) rp[d * (N_NODES + 1) + N_NODES] = s[127];
}

__global__ void scanC_kernel(const int* __restrict__ tmp,
                             const int* __restrict__ chunk_off,
                             int* __restrict__ rp, int* __restrict__ cursor) {
  int d = blockIdx.y;
  int i = blockIdx.x * SCAN_CHUNK + threadIdx.x;
  if (i < N_NODES) {
    int v = tmp[d * N_NODES + i] + chunk_off[d * SCAN_BLOCKS + blockIdx.x];
    rp[d * (N_NODES + 1) + i] = v;
    cursor[d * N_NODES + i] = v;
  }
}

// rel-scatter producing perm AND the dst-keyed col lists in one pass
__global__ void scatter_all_kernel(const int* __restrict__ rel,
                                   const int* __restrict__ dep,
                                   const int* __restrict__ gov,
                                   const int* __restrict__ block_offset,
                                   int* __restrict__ cursor,
                                   int* __restrict__ perm,
                                   int* __restrict__ colf,
                                   int* __restrict__ colr) {
  __shared__ int cur[N_REL];
  if (threadIdx.x < N_REL)
    cur[threadIdx.x] = block_offset[blockIdx.x * N_REL + threadIdx.x];
  __syncthreads();
  int beg = blockIdx.x * SORT_CHUNK;
  int end = min(beg + SORT_CHUNK, N_EDGES);
  for (int e = beg + threadIdx.x; e < end; e += blockDim.x) {
    int pos = atomicAdd(&cur[rel[e]], 1);  // LDS atomic, cheap
    perm[pos] = e;
    colf[atomicAdd(&cursor[dep[e]], 1)] = pos;             // fwd msg pos -> dep
    colr[atomicAdd(&cursor[N_NODES + gov[e]], 1)] = pos;   // rev msg pos -> gov
  }
}

// ---- mega GEMM: buckets 0..9 fwd-edge, 10..19 rev-edge, 20 self ----------
// Edge buckets write bf16 msg rows (linear slots) in C/D-permuted column
// order: short at row*DIM + nb + lm*4 + i holds col nb + i*16 + lm.
// Self bucket writes fp32 directly to out (initializes it for reduce's RMW).

__global__ __launch_bounds__(256, 2)
void mega_gemm_kernel(const unsigned short* __restrict__ xbf,
                      const unsigned short* __restrict__ wt,
                      const float* __restrict__ b_self,
                      const float* __restrict__ b_fwd,
                      const float* __restrict__ b_rev,
                      const int* __restrict__ perm,
                      const int* __restrict__ rel_start,
                      const int* __restrict__ dep,
                      const int* __restrict__ gov,
                      unsigned short* __restrict__ msg,
                      float* __restrict__ out) {
  const int bkt = blockIdx.y;
  const bool is_self = (bkt == 2 * N_REL);
  const int r = bkt % N_REL;
  const bool fwd = bkt < N_REL;

  int beg, cnt;
  const int* src_idx = fwd ? gov : dep;
  unsigned short* mdir = msg + (fwd ? 0 : (size_t)N_EDGES * DIM);
  if (is_self) { beg = 0; cnt = N_NODES; }
  else { beg = rel_start[r]; cnt = rel_start[r + 1] - beg; }
  const int ntiles = (cnt + 63) >> 6;

  const int tid = threadIdx.x;
  const int wave = tid >> 6, lane = tid & 63;
  const int lm = lane & 15, q = lane >> 4;
  const int nb = wave * 64;

  __shared__ int s_src[64];
  __shared__ unsigned short sA[64 * A_STRIDE];  // 35840 B

  // hoisted, tile-invariant W fragments (128 VGPRs)
  bf16x8 wf[8][4];
  const unsigned short* wbase = wt + (size_t)bkt * DIM * DIM;
  #pragma unroll
  for (int kk = 0; kk < 8; ++kk)
    #pragma unroll
    for (int ni = 0; ni < 4; ++ni)
      wf[kk][ni] = *reinterpret_cast<const bf16x8*>(
          wbase + (size_t)(nb + ni * 16 + lm) * DIM + kk * 32 + q * 8);

  const float* bptr = is_self ? b_self : ((fwd ? b_fwd : b_rev) + r * DIM);
  float bias[4];
  #pragma unroll
  for (int ni = 0; ni < 4; ++ni) bias[ni] = bptr[nb + ni * 16 + lm];

  for (int t = blockIdx.x; t < ntiles; t += gridDim.x) {
    const int tile0 = t << 6;
    const int rows_valid = min(64, cnt - tile0);

    if (tid < 64) {
      int s;
      if (is_self) {
        int rr = tile0 + tid;
        s = rr < N_NODES ? rr : N_NODES - 1;
      } else {
        s = (tid < rows_valid) ? src_idx[perm[beg + tile0 + tid]] : 0;
      }
      s_src[tid] = s;
    }
    __syncthreads();

    // stage 64 gathered x rows into LDS (each row fetched exactly once)
    {
      int half = lane >> 5;        // 0 or 1
      int lcol = lane & 31;        // 16B chunk index within row
      #pragma unroll
      for (int i = 0; i < 8; ++i) {
        int row = wave * 16 + i * 2 + half;
        uint4 v = *reinterpret_cast<const uint4*>(
            xbf + (size_t)s_src[row] * DIM + lcol * 8);
        *reinterpret_cast<uint4*>(sA + row * A_STRIDE + lcol * 8) = v;
      }
    }
    __syncthreads();

    f32x4 acc[4][4];
    #pragma unroll
    for (int mi = 0; mi < 4; ++mi)
      #pragma unroll
      for (int ni = 0; ni < 4; ++ni)
        acc[mi][ni] = (f32x4){0.f, 0.f, 0.f, 0.f};

    // pure LDS-read + MFMA k-loop (W is in registers)
    #pragma unroll
    for (int kk = 0; kk < 8; ++kk) {
      bf16x8 a[4];
      #pragma unroll
      for (int mi = 0; mi < 4; ++mi)
        a[mi] = *reinterpret_cast<const bf16x8*>(
            sA + (mi * 16 + lm) * A_STRIDE + kk * 32 + q * 8);
      #pragma unroll
      for (int mi = 0; mi < 4; ++mi)
        #pragma unroll
        for (int ni = 0; ni < 4; ++ni)
          acc[mi][ni] = __builtin_amdgcn_mfma_f32_16x16x32_bf16(a[mi], wf[kk][ni], acc[mi][ni], 0, 0, 0);
    }

    if (is_self) {
      // direct fp32 stores to out (C/D layout; row = quad*4 + reg)
      #pragma unroll
      for (int mi = 0; mi < 4; ++mi) {
        #pragma unroll
        for (int reg = 0; reg < 4; ++reg) {
          int row = mi * 16 + q * 4 + reg;
          if (row < rows_valid) {
            #pragma unroll
            for (int ni = 0; ni < 4; ++ni)
              out[(size_t)(tile0 + row) * DIM + nb + ni * 16 + lm] =
                  acc[mi][ni][reg] + bias[ni];
          }
        }
      }
    } else {
      // permuted uint2 bf16 stores to linear msg slots
      #pragma unroll
      for (int mi = 0; mi < 4; ++mi) {
        #pragma unroll
        for (int reg = 0; reg < 4; ++reg) {
          int row = mi * 16 + q * 4 + reg;
          if (row < rows_valid) {
            unsigned int p0 = ((unsigned int)f2bf(acc[mi][1][reg] + bias[1]) << 16) |
                              f2bf(acc[mi][0][reg] + bias[0]);
            unsigned int p1 = ((unsigned int)f2bf(acc[mi][3][reg] + bias[3]) << 16) |
                              f2bf(acc[mi][2][reg] + bias[2]);
            uint2 u; u.x = p0; u.y = p1;
            *reinterpret_cast<uint2*>(
                mdir + (size_t)(beg + tile0 + row) * DIM + nb + lm * 4) = u;
          }
        }
      }
    }
    __syncthreads();  // protect s_src/sA for next tile
  }
}

// ---- phase 2: CSR gather-sum, 4-row parallel, uint2 loads, permuted cols -

__global__ void reduce_both_kernel(const unsigned short* __restrict__ msg,
                                   const int* __restrict__ rp,
                                   const int* __restrict__ colf,
                                   const int* __restrict__ colr,
                                   float* __restrict__ out) {
  const int n = blockIdx.x, t = threadIdx.x;
  const int g = t >> 6, lane = t & 63;
  const int b0 = rp[n], e0 = rp[n + 1];
  const int b1 = rp[(N_NODES + 1) + n], e1 = rp[(N_NODES + 1) + n + 1];
  if (e0 <= b0 && e1 <= b1) return;

  float a0 = 0.f, a1 = 0.f, a2 = 0.f, a3 = 0.f;
  for (int j = b0 + g; j < e0; j += 4) {
    int row = colf[j];
    uint2 v = *reinterpret_cast<const uint2*>(msg + (size_t)row * DIM + lane * 4);
    union { unsigned int u; float f; } c;
    c.u = v.x << 16;          a0 += c.f;
    c.u = v.x & 0xffff0000u;  a1 += c.f;
    c.u = v.y << 16;          a2 += c.f;
    c.u = v.y & 0xffff0000u;  a3 += c.f;
  }
  for (int j = b1 + g; j < e1; j += 4) {
    int row = colr[j];
    uint2 v = *reinterpret_cast<const uint2*>(
        msg + (size_t)(N_EDGES + row) * DIM + lane * 4);
    union { unsigned int u; float f; } c;
    c.u = v.x << 16;          a0 += c.f;
    c.u = v.x & 0xffff0000u;  a1 += c.f;
    c.u = v.y << 16;          a2 += c.f;
    c.u = v.y & 0xffff0000u;  a3 += c.f;
  }

  // invert the storage permutation: short i of thread's uint2 is column
  // (lane>>4)*64 + i*16 + (lane&15)
  __shared__ float part[4][DIM];
  const int cb = (lane >> 4) * 64 + (lane & 15);
  part[g][cb +  0] = a0;
  part[g][cb + 16] = a1;
  part[g][cb + 32] = a2;
  part[g][cb + 48] = a3;
  __syncthreads();
  float s = part[0][t] + part[1][t] + part[2][t] + part[3][t];
  out[(size_t)n * DIM + t] += s;
}

// ---- fallback: single-phase atomic scatter (if ws too small) -------------

__global__ __launch_bounds__(256, 2)
void self_gemm_kernel(const unsigned short* __restrict__ xbf,
                      const unsigned short* __restrict__ wt_self,
                      const float* __restrict__ b_self,
                      float* __restrict__ out) {
  const int tid = threadIdx.x;
  const int wave = tid >> 6, lane = tid & 63;
  const int lm = lane & 15, q = lane >> 4;
  const int nb = wave * 64;

  bf16x8 wf[8][4];
  #pragma unroll
  for (int kk = 0; kk < 8; ++kk)
    #pragma unroll
    for (int ni = 0; ni < 4; ++ni)
      wf[kk][ni] = *reinterpret_cast<const bf16x8*>(
          wt_self + (size_t)(nb + ni * 16 + lm) * DIM + kk * 32 + q * 8);

  float bias[4];
  #pragma unroll
  for (int ni = 0; ni < 4; ++ni) bias[ni] = b_self[nb + ni * 16 + lm];

  const int ntiles = (N_NODES + 63) / 64;
  for (int t = blockIdx.x; t < ntiles; t += gridDim.x) {
    const int row0 = t * 64;
    const unsigned short* xr[4];
    #pragma unroll
    for (int mi = 0; mi < 4; ++mi) {
      int r = row0 + mi * 16 + lm;
      int rc = r < N_NODES ? r : N_NODES - 1;
      xr[mi] = xbf + (size_t)rc * DIM + q * 8;
    }

    f32x4 acc[4][4];
    #pragma unroll
    for (int mi = 0; mi < 4; ++mi)
      #pragma unroll
      for (int ni = 0; ni < 4; ++ni)
        acc[mi][ni] = (f32x4){0.f, 0.f, 0.f, 0.f};

    #pragma unroll
    for (int kk = 0; kk < 8; ++kk) {
      bf16x8 a[4];
      #pragma unroll
      for (int mi = 0; mi < 4; ++mi)
        a[mi] = *reinterpret_cast<const bf16x8*>(xr[mi] + kk * 32);
      #pragma unroll
      for (int mi = 0; mi < 4; ++mi)
        #pragma unroll
        for (int ni = 0; ni < 4; ++ni)
          acc[mi][ni] = __builtin_amdgcn_mfma_f32_16x16x32_bf16(a[mi], wf[kk][ni], acc[mi][ni], 0, 0, 0);
    }

    #pragma unroll
    for (int mi = 0; mi < 4; ++mi) {
      #pragma unroll
      for (int reg = 0; reg < 4; ++reg) {
        int row = row0 + mi * 16 + q * 4 + reg;
        if (row < N_NODES) {
          #pragma unroll
          for (int ni = 0; ni < 4; ++ni)
            out[(size_t)row * DIM + nb + ni * 16 + lm] = acc[mi][ni][reg] + bias[ni];
        }
      }
    }
  }
}

__global__ void edge_gemm_atomic_kernel(const unsigned short* __restrict__ xbf,
                                        const unsigned short* __restrict__ wt,
                                        const float* __restrict__ b_fwd,
                                        const float* __restrict__ b_rev,
                                        const int* __restrict__ perm,
                                        const int* __restrict__ rel_start,
                                        const int* __restrict__ dep,
                                        const int* __restrict__ gov,
                                        float* __restrict__ out) {
  const int bucket = blockIdx.y;
  const int r = bucket % N_REL;
  const bool fwd = bucket < N_REL;
  const int beg = rel_start[r];
  const int cnt = rel_start[r + 1] - beg;
  const int ntiles = (cnt + 63) >> 6;

  const int tid = threadIdx.x;
  const int wave = tid >> 6, lane = tid & 63;
  const int lm = lane & 15, q = lane >> 4;
  const int nb = wave * 64;

  __shared__ int s_src[64], s_dst[64];

  const unsigned short* wr[4];
  #pragma unroll
  for (int ni = 0; ni < 4; ++ni)
    wr[ni] = wt + (size_t)bucket * DIM * DIM + (size_t)(nb + ni * 16 + lm) * DIM + q * 8;

  const float* bptr = (fwd ? b_fwd : b_rev) + r * DIM;
  float bias[4];
  #pragma unroll
  for (int ni = 0; ni < 4; ++ni) bias[ni] = bptr[nb + ni * 16 + lm];

  for (int t = blockIdx.x; t < ntiles; t += gridDim.x) {
    const int tile0 = t << 6;
    const int rows_valid = min(64, cnt - tile0);

    if (tid < 64) {
      int s = 0, d = -1;
      if (tid < rows_valid) {
        int e = perm[beg + tile0 + tid];
        int gv = gov[e], dp = dep[e];
        s = fwd ? gv : dp;
        d = fwd ? dp : gv;
      }
      s_src[tid] = s;
      s_dst[tid] = d;
    }
    __syncthreads();

    const unsigned short* xr[4];
    #pragma unroll
    for (int mi = 0; mi < 4; ++mi)
      xr[mi] = xbf + (size_t)s_src[mi * 16 + lm] * DIM + q * 8;

    f32x4 acc[4][4];
    #pragma unroll
    for (int mi = 0; mi < 4; ++mi)
      #pragma unroll
      for (int ni = 0; ni < 4; ++ni)
        acc[mi][ni] = (f32x4){0.f, 0.f, 0.f, 0.f};

    #pragma unroll
    for (int k0 = 0; k0 < DIM; k0 += 32) {
      bf16x8 a[4], b[4];
      #pragma unroll
      for (int mi = 0; mi < 4; ++mi) a[mi] = *reinterpret_cast<const bf16x8*>(xr[mi] + k0);
      #pragma unroll
      for (int ni = 0; ni < 4; ++ni) b[ni] = *reinterpret_cast<const bf16x8*>(wr[ni] + k0);
      #pragma unroll
      for (int mi = 0; mi < 4; ++mi)
        #pragma unroll
        for (int ni = 0; ni < 4; ++ni)
          acc[mi][ni] = __builtin_amdgcn_mfma_f32_16x16x32_bf16(a[mi], b[ni], acc[mi][ni], 0, 0, 0);
    }

    #pragma unroll
    for (int mi = 0; mi < 4; ++mi) {
      #pragma unroll
      for (int reg = 0; reg < 4; ++reg) {
        int row = mi * 16 + q * 4 + reg;
        if (row < rows_valid) {
          int dst = s_dst[row];
          float* op = out + (size_t)dst * DIM + nb + lm;
          #pragma unroll
          for (int ni = 0; ni < 4; ++ni)
            atomicAdd(op + ni * 16, acc[mi][ni][reg] + bias[ni]);
        }
      }
    }
    __syncthreads();
  }
}

// ---- launch --------------------------------------------------------------

extern "C" void kernel_launch(void* const* d_in, const int* in_sizes, int n_in,
                              void* d_out, int out_size, void* d_ws, size_t ws_size,
                              hipStream_t stream) {
  const float* x      = (const float*)d_in[0];
  const float* W_self = (const float*)d_in[1];
  const float* b_self = (const float*)d_in[2];
  const float* W_fwd  = (const float*)d_in[3];
  const float* b_fwd  = (const float*)d_in[4];
  const float* W_rev  = (const float*)d_in[5];
  const float* b_rev  = (const float*)d_in[6];
  const int* dep = (const int*)d_in[7];
  const int* rel = (const int*)d_in[8];
  const int* gov = (const int*)d_in[9];
  float* out = (float*)d_out;

  char* base = (char*)d_ws;
  size_t off = 0;
  auto alloc = [&](size_t bytes) -> char* {
    char* p = base + off;
    off = (off + bytes + 15) & ~(size_t)15;
    return p;
  };

  unsigned short* xbf = (unsigned short*)alloc((size_t)N_NODES * DIM * 2);   // 15.36 MB
  unsigned short* wt  = (unsigned short*)alloc((size_t)21 * DIM * DIM * 2);  // 2.75 MB
  int* perm          = (int*)alloc((size_t)N_EDGES * 4);
  int* rel_start     = (int*)alloc(16 * 4);
  int* block_counts  = (int*)alloc(SORT_BLOCKS * N_REL * 4);
  int* block_offset  = (int*)alloc(SORT_BLOCKS * N_REL * 4);
  int* cnt       = (int*)alloc((size_t)2 * N_NODES * 4);
  int* tmp       = (int*)alloc((size_t)2 * N_NODES * 4);
  int* sums      = (int*)alloc((size_t)2 * SCAN_BLOCKS * 4);
  int* chunk_off = (int*)alloc((size_t)2 * SCAN_BLOCKS * 4);
  int* rp        = (int*)alloc((size_t)2 * (N_NODES + 1) * 4);
  int* cursor    = (int*)alloc((size_t)2 * N_NODES * 4);
  int* colf      = (int*)alloc((size_t)N_EDGES * 4);
  int* colr      = (int*)alloc((size_t)N_EDGES * 4);
  unsigned short* msg = (unsigned short*)alloc((size_t)2 * N_EDGES * DIM * 2);  // 153.6 MB
  const bool two_phase = (off <= ws_size);

  prep_kernel<<<PREP_XB + PREP_WB + PREP_ZB, 256, 0, stream>>>(
      x, W_fwd, W_rev, W_self, xbf, wt, cnt);
  hist_all_kernel<<<SORT_BLOCKS, 256, 0, stream>>>(rel, dep, gov, block_counts, cnt);
  scan_rel_kernel<<<1, 64, 0, stream>>>(block_counts, rel_start, block_offset);
  scanA_kernel<<<dim3(SCAN_BLOCKS, 2), SCAN_CHUNK, 0, stream>>>(cnt, tmp, sums);
  scanB_kernel<<<2, 128, 0, stream>>>(sums, chunk_off, rp);
  scanC_kernel<<<dim3(SCAN_BLOCKS, 2), SCAN_CHUNK, 0, stream>>>(tmp, chunk_off, rp, cursor);
  scatter_all_kernel<<<SORT_BLOCKS, 256, 0, stream>>>(
      rel, dep, gov, block_offset, cursor, perm, colf, colr);

  if (two_phase) {
    // buckets 0..19 edges -> msg; bucket 20 self -> out (init for reduce RMW)
    mega_gemm_kernel<<<dim3(48, 2 * N_REL + 1), 256, 0, stream>>>(
        xbf, wt, b_self, b_fwd, b_rev, perm, rel_start, dep, gov, msg, out);
    reduce_both_kernel<<<N_NODES, 256, 0, stream>>>(msg, rp, colf, colr, out);
  } else {
    self_gemm_kernel<<<120, 256, 0, stream>>>(
        xbf, wt + (size_t)20 * DIM * DIM, b_self, out);
    edge_gemm_atomic_kernel<<<dim3(260, 20), 256, 0, stream>>>(
        xbf, wt, b_fwd, b_rev, perm, rel_start, dep, gov, out);
  }
}